// Round 1
// baseline (38.343 us; speedup 1.0000x reference)
//
#include <hip/hip_runtime.h>

// MutualInformation2D: B=32 batches, N=2*512*512=524288 points/batch.
// hist (uint) per batch in d_ws, MI in double, scalar out = -mean(mi).

#define BINS 32
#define NBINS2 1024
#define NBATCH 32
#define N_PER_BATCH (2 * 512 * 512)      // 524288
#define BLOCKS_PER_BATCH 64
#define CHUNK (N_PER_BATCH / BLOCKS_PER_BATCH)  // 8192
#define THREADS 256

__global__ __launch_bounds__(THREADS) void zero_kernel(unsigned* __restrict__ hist,
                                                       double* __restrict__ mi,
                                                       float* __restrict__ out) {
    int i = blockIdx.x * THREADS + threadIdx.x;
    if (i < NBATCH * NBINS2) hist[i] = 0u;
    if (i < NBATCH) mi[i] = 0.0;
    if (i == 0) out[0] = 0.0f;
}

__global__ __launch_bounds__(THREADS) void hist_kernel(const float* __restrict__ x,
                                                       const float* __restrict__ y,
                                                       unsigned* __restrict__ hist) {
    __shared__ unsigned h[NBINS2];
    for (int i = threadIdx.x; i < NBINS2; i += THREADS) h[i] = 0u;
    __syncthreads();

    const int b   = blockIdx.x / BLOCKS_PER_BATCH;
    const int blk = blockIdx.x % BLOCKS_PER_BATCH;
    const long base = (long)b * N_PER_BATCH + (long)blk * CHUNK;
    const float4* xv = (const float4*)(x + base);
    const float4* yv = (const float4*)(y + base);
    const int nvec = CHUNK / 4;  // 2048

    for (int i = threadIdx.x; i < nvec; i += THREADS) {
        float4 a = xv[i];
        float4 t = yv[i];
        float ax[4] = {a.x, a.y, a.z, a.w};
        float ty[4] = {t.x, t.y, t.z, t.w};
#pragma unroll
        for (int k = 0; k < 4; ++k) {
            // Exact float32 replication of the reference binning.
            float u = (ax[k] + 1.0f) * 0.5f;
            float v = (ty[k] + 1.0f) * 0.5f;
            bool ok = (u >= 0.0f) & (u <= 1.0f) & (v >= 0.0f) & (v <= 1.0f);
            if (ok) {
                int iu = (int)(u * 32.0f); if (iu > 31) iu = 31;
                int iv = (int)(v * 32.0f); if (iv > 31) iv = 31;
                atomicAdd(&h[iu * BINS + iv], 1u);
            }
        }
    }
    __syncthreads();

    unsigned* g = hist + b * NBINS2;
    for (int i = threadIdx.x; i < NBINS2; i += THREADS) {
        unsigned v = h[i];
        if (v) atomicAdd(&g[i], v);
    }
}

__global__ __launch_bounds__(256) void mi_kernel(const unsigned* __restrict__ hist,
                                                 double* __restrict__ mi_out) {
    __shared__ unsigned c[NBINS2];
    __shared__ unsigned px[BINS];
    __shared__ unsigned py[BINS];
    __shared__ double red[4];

    const int b = blockIdx.x;
    const unsigned* g = hist + b * NBINS2;
    for (int i = threadIdx.x; i < NBINS2; i += 256) c[i] = g[i];
    __syncthreads();

    if (threadIdx.x < 32) {
        unsigned s = 0;
        for (int j = 0; j < 32; ++j) s += c[threadIdx.x * BINS + j];
        px[threadIdx.x] = s;
    } else if (threadIdx.x < 64) {
        int col = threadIdx.x - 32;
        unsigned s = 0;
        for (int j = 0; j < 32; ++j) s += c[j * BINS + col];
        py[col] = s;
    }
    __syncthreads();

    unsigned total = 0;
    for (int j = 0; j < 32; ++j) total += px[j];
    const double T = (double)total;

    double acc = 0.0;
    for (int i = threadIdx.x; i < NBINS2; i += 256) {
        unsigned cc = c[i];
        if (cc) {
            int r = i >> 5, col = i & 31;
            acc += (double)cc * log((double)cc * T / ((double)px[r] * (double)py[col]));
        }
    }
    // wave (64-lane) shuffle reduction, fixed order -> deterministic
    for (int off = 32; off > 0; off >>= 1)
        acc += __shfl_down(acc, off, 64);
    int wave = threadIdx.x >> 6;
    if ((threadIdx.x & 63) == 0) red[wave] = acc;
    __syncthreads();
    if (threadIdx.x == 0) {
        double s = red[0] + red[1] + red[2] + red[3];
        mi_out[b] = s / T;
    }
}

__global__ void finalize_kernel(const double* __restrict__ mi, float* __restrict__ out) {
    if (threadIdx.x == 0) {
        double s = 0.0;
        for (int i = 0; i < NBATCH; ++i) s += mi[i];
        out[0] = (float)(-s / (double)NBATCH);
    }
}

extern "C" void kernel_launch(void* const* d_in, const int* in_sizes, int n_in,
                              void* d_out, int out_size, void* d_ws, size_t ws_size,
                              hipStream_t stream) {
    const float* x = (const float*)d_in[0];
    const float* y = (const float*)d_in[1];
    float* out = (float*)d_out;

    unsigned* hist = (unsigned*)d_ws;                                   // 32*1024*4 = 128 KiB
    double* mi = (double*)((char*)d_ws + NBATCH * NBINS2 * sizeof(unsigned)); // 256 B

    zero_kernel<<<(NBATCH * NBINS2 + THREADS - 1) / THREADS, THREADS, 0, stream>>>(hist, mi, out);
    hist_kernel<<<NBATCH * BLOCKS_PER_BATCH, THREADS, 0, stream>>>(x, y, hist);
    mi_kernel<<<NBATCH, 256, 0, stream>>>(hist, mi);
    finalize_kernel<<<1, 64, 0, stream>>>(mi, out);
}